// Round 1
// baseline (106.444 us; speedup 1.0000x reference)
//
#include <hip/hip_runtime.h>

// Tropical (max-plus) linear map: y[b,o] = max_i (x[b,i] + W[o,i])
// B=512, I=1024, O=1024, fp32.
//
// GEMM-style tiling on the fp32 VALU (no MFMA possible for max-plus):
//   BT=32 x OT=64 output tile per block, 256 threads, 2x4 regs/thread.
//   Grid = 16x16 = 256 blocks -> 1 block/CU on 256 CUs.
//   K staged in KT=64 chunks via LDS (transposed, padded strides to keep
//   staging-write bank conflicts <=2-way, which is free).
//   Register prefetch double-buffering hides global latency under compute.
//   Inner loop unrolled by 2 in k so the compiler forms v_max3_f32:
//   acc = max3(acc, x_k + w_k, x_{k+1} + w_{k+1})  -> 3 VALU ops / 2 elems.

#define B_DIM 512
#define I_DIM 1024
#define O_DIM 1024
#define BT 32
#define OT 64
#define KT 64
#define NCHUNK (I_DIM / KT)   // 16
#define XS (BT + 1)           // 33  (pad: write conflicts <=2-way)
#define WS (OT + 1)           // 65

__global__ __launch_bounds__(256, 1) void TropicalLinear_kernel(
    const float* __restrict__ x, const float* __restrict__ W,
    float* __restrict__ y)
{
    __shared__ float xs[KT * XS];   // [k][b], 8448 B
    __shared__ float ws[KT * WS];   // [k][o], 16640 B

    const int tid = threadIdx.x;
    const int to  = tid & 15;   // o-direction (fastest -> coalesced C store)
    const int tb  = tid >> 4;   // b-direction
    const int b0  = blockIdx.y * BT;
    const int o0  = blockIdx.x * OT;

    const float4* xg = (const float4*)x;
    const float4* wg = (const float4*)W;

    float4 xr[2];   // prefetch regs: x chunk = 32x64 floats = 512 float4
    float4 wr[4];   // w chunk = 64x64 floats = 1024 float4

    // ---- prefetch chunk 0 (coalesced: consecutive lanes -> consecutive float4)
    #pragma unroll
    for (int s = 0; s < 2; ++s) {
        const int f = tid + 256 * s;
        const int r = f >> 4, c4 = f & 15;
        xr[s] = xg[(b0 + r) * (I_DIM / 4) + c4];
    }
    #pragma unroll
    for (int s = 0; s < 4; ++s) {
        const int f = tid + 256 * s;
        const int r = f >> 4, c4 = f & 15;
        wr[s] = wg[(o0 + r) * (I_DIM / 4) + c4];
    }

    float acc[2][4];
    #pragma unroll
    for (int i = 0; i < 2; ++i)
        #pragma unroll
        for (int j = 0; j < 4; ++j)
            acc[i][j] = -3.402823466e38f;

    for (int kc = 0; kc < NCHUNK; ++kc) {
        __syncthreads();   // previous chunk's LDS reads done

        // ---- staged regs -> LDS (transposed: [k][b], [k][o])
        #pragma unroll
        for (int s = 0; s < 2; ++s) {
            const int f = tid + 256 * s;
            const int r = f >> 4, c4 = f & 15;
            xs[(4 * c4 + 0) * XS + r] = xr[s].x;
            xs[(4 * c4 + 1) * XS + r] = xr[s].y;
            xs[(4 * c4 + 2) * XS + r] = xr[s].z;
            xs[(4 * c4 + 3) * XS + r] = xr[s].w;
        }
        #pragma unroll
        for (int s = 0; s < 4; ++s) {
            const int f = tid + 256 * s;
            const int r = f >> 4, c4 = f & 15;
            ws[(4 * c4 + 0) * WS + r] = wr[s].x;
            ws[(4 * c4 + 1) * WS + r] = wr[s].y;
            ws[(4 * c4 + 2) * WS + r] = wr[s].z;
            ws[(4 * c4 + 3) * WS + r] = wr[s].w;
        }
        __syncthreads();

        // ---- prefetch next chunk (in flight during compute)
        if (kc + 1 < NCHUNK) {
            const int k4 = (kc + 1) * (KT / 4);
            #pragma unroll
            for (int s = 0; s < 2; ++s) {
                const int f = tid + 256 * s;
                const int r = f >> 4, c4 = f & 15;
                xr[s] = xg[(b0 + r) * (I_DIM / 4) + k4 + c4];
            }
            #pragma unroll
            for (int s = 0; s < 4; ++s) {
                const int f = tid + 256 * s;
                const int r = f >> 4, c4 = f & 15;
                wr[s] = wg[(o0 + r) * (I_DIM / 4) + k4 + c4];
            }
        }

        // ---- compute: unroll-2 in k so fmaxf(fmaxf(s0,s1)) -> v_max3_f32
        #pragma unroll 4
        for (int k = 0; k < KT; k += 2) {
            float xa[2], xb[2];
            xa[0] = xs[k * XS + tb];
            xa[1] = xs[k * XS + tb + 16];
            xb[0] = xs[(k + 1) * XS + tb];
            xb[1] = xs[(k + 1) * XS + tb + 16];
            float w0[4], w1[4];
            #pragma unroll
            for (int j = 0; j < 4; ++j) {
                w0[j] = ws[k * WS + 4 * to + j];
                w1[j] = ws[(k + 1) * WS + 4 * to + j];
            }
            #pragma unroll
            for (int i = 0; i < 2; ++i)
                #pragma unroll
                for (int j = 0; j < 4; ++j) {
                    const float s0 = xa[i] + w0[j];
                    const float s1 = xb[i] + w1[j];
                    acc[i][j] = fmaxf(acc[i][j], fmaxf(s0, s1));
                }
        }
    }

    // ---- epilogue: coalesced float4 stores (4 consecutive o per thread)
    #pragma unroll
    for (int i = 0; i < 2; ++i) {
        float4 v = make_float4(acc[i][0], acc[i][1], acc[i][2], acc[i][3]);
        *(float4*)&y[(b0 + tb + 16 * i) * O_DIM + o0 + 4 * to] = v;
    }
}

extern "C" void kernel_launch(void* const* d_in, const int* in_sizes, int n_in,
                              void* d_out, int out_size, void* d_ws, size_t ws_size,
                              hipStream_t stream) {
    const float* x = (const float*)d_in[0];
    const float* W = (const float*)d_in[1];
    float* y = (float*)d_out;
    dim3 grid(O_DIM / OT, B_DIM / BT);   // 16 x 16 = 256 blocks
    dim3 block(256);
    TropicalLinear_kernel<<<grid, block, 0, stream>>>(x, W, y);
}